// Round 8
// baseline (173.308 us; speedup 1.0000x reference)
//
#include <hip/hip_runtime.h>
#include <cmath>

// ---------------------------------------------------------------------------
// Bit-exact replication of the reference's f32 cumsum TREE (JAX associative
// scan), validated rounds 5-11 (absmax 1.831e-3 — bf16-quantized compare;
// non-chaotic-path deltas <1e-6 are free).
// Round 14 (WIN, 137.8us): LDS-transpose epilogue; synth4 48.3us @92% VALU.
// Round 18 (WIN, 136.7us): S-interface (scan stops at L5; synth4 recon-
//   structs G's in-group, bit-exact). FETCH 15.8->11.6MB as predicted.
// Budget model (rounds 2/3/7): f0up ~8 + scan4 ~35-38 (straggler: 24KB LDS
//   -> 6 blk/CU -> 1536 resident < 1600) + synth4 ~50 + ~14.5us/dispatch x3.
// Round 19: fuse to 2 dispatches using only pre-validated pieces:
//   k_scan5 = inline-interp leaves (r16-validated DAG) + L5-leaf tree
//   (r17-validated bracketing, 2993 floats = 12KB LDS -> 8 blk/CU -> no
//   straggler) + S emit (r18-validated) + out zero-init (r16-validated).
//   k_synth4 = r18 k-loop byte-identical + r16-validated inline-u setup.
// ---------------------------------------------------------------------------
#pragma clang fp contract(off)

#define SRF   48000.0f
#define NYQF  21600.0f                    // fp32(48000*0.45), exact
constexpr float  TWO_PI_F  = 6.283185307179586476925286766559f;  // 0x40C90FDB
constexpr double INV_2PI_D = 0.15915494309189533576888376337251;
constexpr float  RC1 = (float)INV_2PI_D;
constexpr float  RC2 = (float)(INV_2PI_D - (double)RC1);
constexpr double INV_SR_D = 1.0 / 48000.0;
constexpr float  DD1 = (float)INV_SR_D;
constexpr float  DD2 = (float)(INV_SR_D - (double)DD1);

__device__ __forceinline__ float hsin_rev(float r) {  // sin(2*pi*r)
#if __has_builtin(__builtin_amdgcn_sinf)
    return __builtin_amdgcn_sinf(r);                  // v_sin_f32: revolutions
#else
    return __sinf(r * TWO_PI_F);
#endif
}

// Correctly-rounded t/48000 via double-float mul (== IEEE f32 divide here;
// proved: no halfway cases, err 2^-47 << 2^-33.5 boundary distance).
__device__ __forceinline__ float div48000(float t) {
    float h = t * DD1;
    float r = __builtin_fmaf(t, DD1, -h);
    float s = __builtin_fmaf(t, DD2, r);
    return h + s;
}

// sin(ph) for f32 ph: double-float reduction to revolutions (|err|<=2^-25 rev)
__device__ __forceinline__ float sin_phase(float ph) {
    float h  = ph * RC1;
    float r  = __builtin_fmaf(ph, RC1, -h);
    float s  = __builtin_fmaf(ph, RC2, r);
    float nn = __builtin_rintf(h);
    float fr = (h - nn) + s;
    return hsin_rev(fr);
}

// group-of-4 broadcast: value of lane (lane&~3)+idx  (idx=0..3 static)
template <int IDX>
__device__ __forceinline__ float grp4_bcast(float v, int lb) {
#if __has_builtin(__builtin_amdgcn_ds_swizzle)
    // BitMode: offset = (xor<<10)|(or<<5)|and ; and=0x1C clears low 2 bits
    constexpr int imm = (IDX << 5) | 0x1C;
    return __int_as_float(__builtin_amdgcn_ds_swizzle(__float_as_int(v), imm));
#else
    return __shfl(v, lb + IDX);
#endif
}

// group-of-8 broadcast: value of lane (lane&~7)
__device__ __forceinline__ float grp8_bcast0(float v, int lane) {
#if __has_builtin(__builtin_amdgcn_ds_swizzle)
    // BitMode: and=0x18 clears low 3 bits, or=0, xor=0
    return __int_as_float(__builtin_amdgcn_ds_swizzle(__float_as_int(v), 0x0018));
#else
    return __shfl(v, lane & ~7);
#endif
}

// kc[b,k] = fp32(k * fp32(sqrt(fp32(1 + fp32(inh*k^2)))))  -- np/jnp-exact
__device__ __forceinline__ float kcval(int k, float ib) {
    float kf = (float)(k + 1);
    float k2 = kf * kf;
    float m  = ib * k2;
    float s1 = 1.0f + m;
    float st = (float)sqrt((double)s1);
    return kf * st;
}

// np-exact linear interp of f0 at sample j (identical expression to the old
// k_f0up kernel — bitwise-equal u values; validated round 16).
__device__ __forceinline__ float f0interp(const float* __restrict__ fb,
        int j, int T, float pf, float tmaxf) {
    float pos = ((float)j + 0.5f);
    pos = pos * pf;
    pos = pos - 0.5f;
    pos = fmaxf(pos, 0.0f);
    pos = fminf(pos, tmaxf);
    int   i0 = (int)pos;
    int   i1 = min(i0 + 1, T - 1);
    float w  = pos - (float)i0;
    float omw = 1.0f - w;
    return fb[i0] * omw + fb[i1] * w;
}

// ---- K1 (fallback path only): f0_up + zero-init of out ---------------------
__global__ void __launch_bounds__(256) k_f0up(const float* __restrict__ f0,
        float* __restrict__ f0up, float* __restrict__ out,
        int T, int n, float pf) {
    int j = blockIdx.x * 256 + threadIdx.x;
    int b = blockIdx.y;
    if (j >= n) return;
    const float* fb = f0 + b * T;
    f0up[(size_t)b * n + j] = f0interp(fb, j, T, pf, (float)(T - 1));
    out[(size_t)b * n + j]  = 0.0f;
}

// ---- K2a: per (b,k) L5 scan; leaves from inline interp; 12KB tree ----------
// Emits S rows: sp[0] = 0, sp[1+i] = inclusive-L5-scan[i]  (len5+1 floats).
// Also zero-inits this (k,b)'s slice of out (completes before synth4 runs).
__global__ void __launch_bounds__(256) k_scan5(const float* __restrict__ f0,
        const float* __restrict__ inh, float* __restrict__ scanS,
        float* __restrict__ outz, int N, int n, int T, float pf) {
    __shared__ float lv[3008];                 // levels L5..root: 2993 floats
    const int k   = blockIdx.x;
    const int b   = blockIdx.y;
    const int tid = threadIdx.x;
    const float kc = kcval(k, inh[b]);
    const float* fb = f0 + b * T;
    const float tmaxf = (float)(T - 1);
    const int len5 = n >> 5;

    // zero-init out slice (harness poisons out; we own it). Stream order
    // guarantees completion before synth4's atomics.
    {
        const int chunk = (n + N - 1) / N;
        const int z0 = k * chunk;
        for (int i = tid; i < chunk; i += 256) {
            int j = z0 + i;
            if (j < n) outz[(size_t)b * n + j] = 0.0f;
        }
    }

    // leaf: L5[i] = fl(L4(2i)+L4(2i+1)); L4 from the round-14 DAG with u's
    // interpolated inline (round-16-validated, bitwise == f0up values).
    auto l2of = [&](int jb) -> float {
        float a0 = div48000(TWO_PI_F * (kc * f0interp(fb, jb + 0, T, pf, tmaxf)));
        float a1 = div48000(TWO_PI_F * (kc * f0interp(fb, jb + 1, T, pf, tmaxf)));
        float a2 = div48000(TWO_PI_F * (kc * f0interp(fb, jb + 2, T, pf, tmaxf)));
        float a3 = div48000(TWO_PI_F * (kc * f0interp(fb, jb + 3, T, pf, tmaxf)));
        return (a0 + a1) + (a2 + a3);
    };
    auto l4of = [&](int j) -> float {
        float s01 = l2of(16 * j)     + l2of(16 * j + 4);
        float s23 = l2of(16 * j + 8) + l2of(16 * j + 12);
        return s01 + s23;
    };
    for (int i = tid; i < len5; i += 256)
        lv[i] = l4of(2*i) + l4of(2*i + 1);     // upsweep bracketing (r17)
    __syncthreads();

    // upsweep L5 -> root (validated pairing/order)
    int offp = 0, lenp = len5, P = 5;
    for (int l = 6; ; ++l) {
        int lenc = lenp >> 1;
        int offc = offp + lenp;
        for (int i = tid; i < lenc; i += 256)
            lv[offc + i] = lv[offp + 2*i] + lv[offp + 2*i + 1];
        __syncthreads();
        P = l;
        if (lenc == 1) break;
        offp = offc; lenp = lenc;
    }
    // downsweep to L5 (round-5-validated formulas, offsets rebased to L5)
    for (int l = P - 1; l >= 5; --l) {
        int lenl = n >> l;
        int offl = 0;
        for (int m = 5; m < l; ++m) offl += (n >> m);
        float*       arr = lv + offl;
        const float* hi  = lv + offl + lenl;
        int lenh = n >> (l + 1);
        for (int i = tid; i < lenh; i += 256) {
            float v = hi[i];
            int e = 2*i + 2;
            if (e < lenl) arr[e] = v + arr[e];
            arr[2*i + 1] = v;
        }
        __syncthreads();
    }
    // lv[0..len5) = inclusive L5 scan; emit padded S row.
    float* sp = scanS + (size_t)(b * N + k) * (len5 + 1);
    if (tid == 0) sp[0] = 0.0f;
    for (int i = tid; i < len5; i += 256) sp[1 + i] = lv[i];
}

// ---- K2b: 4 lanes per 16-j group (r18 k-loop; r16 inline-u setup) ----------
__global__ void __launch_bounds__(256) k_synth4(
        const float* __restrict__ harm, const float* __restrict__ f0,
        const float* __restrict__ inh,  const float* __restrict__ scanS,
        float* __restrict__ out, int B, int T, int N, int n, float pf, int kpg) {
    const int tid  = threadIdx.x;
    const int b    = blockIdx.y;
    const int k0   = blockIdx.z * kpg;
    const int g    = blockIdx.x * 256 + tid;   // global lane id
    const int q    = g >> 2;                   // 16-sample group
    const int c    = g & 3;                    // quarter within group
    const int NG   = n >> 4;
    const int NG5P = (n >> 5) + 1;             // S-row length
    const int kend = min(k0 + kpg, N);
    const int kact = kend - k0;
    const bool valid = q < NG;
    const bool oddq  = (q & 1) != 0;
    const int  si    = (q >> 1) + (q & 1);     // S index this lane loads

    __shared__ float2 amps[8 * 32];            // (a0, a1-a0) x k (span 1024 j)
    __shared__ float  kcs[32];
    __shared__ float  xp[4][256];              // per-wave transpose for stores

    const float ib    = inh[b];
    const float tmaxf = (float)(T - 1);
    for (int i = tid; i < kact; i += 256) kcs[i] = kcval(k0 + i, ib);

    const int j0blk = blockIdx.x * 1024;
    int i0min;
    {
        float p = ((float)j0blk + 0.5f);
        p = p * pf; p = p - 0.5f;
        p = fmaxf(p, 0.0f); p = fminf(p, tmaxf);
        i0min = (int)p;
    }
    for (int idx = tid; idx < 8 * kact; idx += 256) {
        int r = idx / kact, kk = idx - r * kact;
        int r0 = min(i0min + r, T - 1);
        int r1 = min(i0min + r + 1, T - 1);
        float a0 = harm[((size_t)b * T + r0) * N + (k0 + kk)];
        float a1 = harm[((size_t)b * T + r1) * N + (k0 + kk)];
        amps[idx] = make_float2(a0, a1 - a0);  // blend = fmaf(w, d, a0)
    }
    __syncthreads();                           // last block-wide barrier

    float u0=0.f,u1=0.f,u2=0.f,u3=0.f;
    float w0=0.f,w1=0.f,w2=0.f,w3=0.f;
    int   a0o=0,a1o=0,a2o=0,a3o=0;
    float acc0=0.f, acc1=0.f, acc2=0.f, acc3=0.f;
    float um = __builtin_inff();
    if (valid) {
        const float* fb = f0 + b * T;
        const int jb = q * 16 + c * 4;
        // u computed inline — identical expression to old k_f0up (bitwise ==,
        // validated round 16)
        #pragma unroll
        for (int i = 0; i < 4; ++i) {
            float p = ((float)(jb + i) + 0.5f);
            p = p * pf; p = p - 0.5f;
            p = fmaxf(p, 0.0f); p = fminf(p, tmaxf);
            int i0 = (int)p;
            int i1 = min(i0 + 1, T - 1);
            float wv = p - (float)i0;
            float omw = 1.0f - wv;
            float uv = fb[i0] * omw + fb[i1] * wv;
            int aoo  = (i0 - i0min) * kact;
            if (i==0){u0=uv;w0=wv;a0o=aoo;}
            else if (i==1){u1=uv;w1=wv;a1o=aoo;}
            else if (i==2){u2=uv;w2=wv;a2o=aoo;}
            else {u3=uv;w3=wv;a3o=aoo;}
        }
        um = fminf(fminf(u0,u1), fminf(u2,u3));
    }
    // wave-wide min for uniform early break
    #pragma unroll
    for (int off = 32; off > 0; off >>= 1)
        um = fminf(um, __shfl_xor(um, off));
    const float umin = um;
    const int lane = tid & 63;
    const int lb   = lane & ~3;                // group base lane (fallback path)

    if (valid) {
        const float* s4k = scanS + (size_t)(b * N + k0) * NG5P;
        float svc = s4k[si];                   // S[i] (even q) / S[i+1] (odd q)

        for (int k = k0; k < kend; ++k) {
            const int   kk = k - k0;
            const float kc = kcs[kk];
            if (kc * umin >= NYQF) break;      // wave-uniform; kc monotone in k
            const float Sv = svc;
            if (k + 1 < kend) {                // prefetch next k row
                const float* nx = s4k + NG5P;
                svc = nx[si];
                s4k = nx;
            }

            // lane-local increments (bit-exact vs ref elementwise ops)
            float x0 = div48000(TWO_PI_F * (kc * u0));
            float x1 = div48000(TWO_PI_F * (kc * u1));
            float x2 = div48000(TWO_PI_F * (kc * u2));
            float x3 = div48000(TWO_PI_F * (kc * u3));
            float L1p = x0 + x1, L1q = x2 + x3;
            float L2  = L1p + L1q;

            // group L2 partials (FP add commutative bitwise -> exact assoc)
            float s0 = grp4_bcast<0>(L2, lb);
            float s1 = grp4_bcast<1>(L2, lb);
            float s2 = grp4_bcast<2>(L2, lb);
            float s3 = grp4_bcast<3>(L2, lb);
            float t01 = s0 + s1;
            float s23 = s2 + s3;
            float L4v = t01 + s23;             // == l4of bracketing, bit-exact
            // G reconstruction (even lanes compute the deleted downsweep add):
            float G1e = Sv + L4v;              // fl(S[i] + L4[2i]) on even q
            float Gx  = grp8_bcast0(G1e, lane);// supergroup lane0's G1e
            float G0  = oddq ? Gx : Sv;
            float G1  = oddq ? Sv : G1e;

            float b1v = G0 + s0;               // s20
            float b2v = G0 + t01;              // s3v  (g0 + (L2a+L2b))
            float b3v = b2v + s2;              // s22
            float base = (c == 0) ? G0  : (c == 1) ? b1v : (c == 2) ? b2v : b3v;
            float bn   = (c == 0) ? b1v : (c == 1) ? b2v : (c == 2) ? b3v : G1;

            float ph0 = base + x0;
            float ph1 = base + L1p;
            float ph2 = ph1 + x2;
            float ph3 = bn;

            {   float t1 = kc * u0;            // same RN product as ref mask
                if (t1 < NYQF) { float sv = sin_phase(ph0);
                    float2 a = amps[a0o + kk];
                    acc0 = __builtin_fmaf(__builtin_fmaf(w0, a.y, a.x), sv, acc0); } }
            {   float t1 = kc * u1;
                if (t1 < NYQF) { float sv = sin_phase(ph1);
                    float2 a = amps[a1o + kk];
                    acc1 = __builtin_fmaf(__builtin_fmaf(w1, a.y, a.x), sv, acc1); } }
            {   float t1 = kc * u2;
                if (t1 < NYQF) { float sv = sin_phase(ph2);
                    float2 a = amps[a2o + kk];
                    acc2 = __builtin_fmaf(__builtin_fmaf(w2, a.y, a.x), sv, acc2); } }
            {   float t1 = kc * u3;
                if (t1 < NYQF) { float sv = sin_phase(ph3);
                    float2 a = amps[a3o + kk];
                    acc3 = __builtin_fmaf(__builtin_fmaf(w3, a.y, a.x), sv, acc3); } }
        }
    }

    // ---- wave-local transpose epilogue: coalesce atomics to full 64B lines.
    // Lane l owns floats 4l..4l+3 of its wave's contiguous 1KB out span; the
    // LDS bounce makes each atomic instruction cover 64 consecutive words.
    // Per-wave LDS region -> no barrier needed (lgkmcnt orders write->read).
    {
        const int wid  = tid >> 6;
        *(float4*)&xp[wid][4 * lane] = make_float4(acc0, acc1, acc2, acc3);
        const float Nf = (float)N;
        const int jb = blockIdx.x * 1024 + wid * 256;   // wave span [jb, jb+256)
        float* ob = out + (size_t)b * n + jb;
        #pragma unroll
        for (int i = 0; i < 4; ++i) {
            float v  = xp[wid][i * 64 + lane];
            int   jj = jb + i * 64 + lane;
            if (jj < n) atomicAdd(&ob[i * 64 + lane], v / Nf);
        }
    }
}

// ---- Fallback: round-5 proven kernel (atomics, 96 KB LDS) ------------------
__global__ void __launch_bounds__(256) k_scan_synth(
        const float* __restrict__ harm, const float* __restrict__ f0up,
        const float* __restrict__ inh,  float* __restrict__ out,
        int B, int T, int N, int n, float pf) {
    extern __shared__ float lv[];
    const int k   = blockIdx.x;
    const int b   = blockIdx.y;
    const int tid = threadIdx.x;
    const float kc = kcval(k, inh[b]);
    const float* fb = f0up + (size_t)b * n;

    auto inc = [&](int j) -> float {
        float u    = fb[j];
        float inst = kc * u;
        float tt   = TWO_PI_F * inst;
        return tt / SRF;
    };

    const int len1 = n >> 1;
    {
        const float4* f4 = (const float4*)fb;
        for (int i = tid; i < (n >> 2); i += 256) {
            float4 u = f4[i];
            float a0 = (TWO_PI_F * (kc * u.x)) / SRF;
            float a1 = (TWO_PI_F * (kc * u.y)) / SRF;
            float a2 = (TWO_PI_F * (kc * u.z)) / SRF;
            float a3 = (TWO_PI_F * (kc * u.w)) / SRF;
            lv[i] = (a0 + a1) + (a2 + a3);
        }
    }
    __syncthreads();
    int offp = 0, lenp = n >> 2, P = 2;
    for (int l = 3; ; ++l) {
        int lenc = lenp >> 1;
        int offc = offp + lenp;
        for (int i = tid; i < lenc; i += 256)
            lv[offc + i] = lv[offp + 2*i] + lv[offp + 2*i + 1];
        __syncthreads();
        P = l;
        if (lenc == 1) break;
        offp = offc; lenp = lenc;
    }
    for (int l = P - 1; l >= 2; --l) {
        int lenl = n >> l;
        int offl = 0;
        for (int m = 2; m < l; ++m) offl += (n >> m);
        float*       arr = lv + offl;
        const float* hi  = lv + offl + lenl;
        int lenh = n >> (l + 1);
        for (int i = tid; i < lenh; i += 256) {
            float v = hi[i];
            int e = 2*i + 2;
            if (e < lenl) arr[e] = v + arr[e];
            arr[2*i + 1] = v;
        }
        __syncthreads();
    }
    const float* scan2 = lv;

    const float  tmaxf = (float)(T - 1);
    const float  invN  = 1.0f / (float)N;
    const float* hb    = harm + (size_t)b * T * N + k;
    float*       ob    = out + (size_t)b * n;

    auto emit = [&](int j, float ph) {
        float u    = fb[j];
        float inst = kc * u;
        if (!(inst < NYQF)) return;
        double pr = (double)ph * INV_2PI_D;
        double fr = pr - rint(pr);
        float  sv = hsin_rev((float)fr);
        float pos = ((float)j + 0.5f);
        pos = pos * pf; pos = pos - 0.5f;
        pos = fmaxf(pos, 0.0f); pos = fminf(pos, tmaxf);
        int   i0 = (int)pos;
        int   i1 = min(i0 + 1, T - 1);
        float w  = pos - (float)i0;
        float a  = hb[(size_t)i0 * N] * (1.0f - w) + hb[(size_t)i1 * N] * w;
        atomicAdd(&ob[j], (a * sv) * invN);
    };

    if (tid == 0) emit(0, inc(0));
    for (int tt = tid; tt < len1; tt += 256) {
        float s1;
        if (tt == 0)      s1 = inc(0) + inc(1);
        else if (tt & 1)  s1 = scan2[(tt - 1) >> 1];
        else              s1 = scan2[(tt >> 1) - 1] + (inc(2*tt) + inc(2*tt + 1));
        emit(2*tt + 1, s1);
        int je = 2*tt + 2;
        if (je < n) emit(je, s1 + inc(je));
    }
}

extern "C" void kernel_launch(void* const* d_in, const int* in_sizes, int n_in,
                              void* d_out, int out_size, void* d_ws, size_t ws_size,
                              hipStream_t stream) {
    const int B = in_sizes[2];                 // 16
    const int T = in_sizes[1] / B;             // 250
    const int N = in_sizes[0] / (B * T);       // 100
    const int n = out_size / B;                // 48000
    const float pf = (float)((double)T / (double)n);

    const float* harm = (const float*)d_in[0];
    const float* f0   = (const float*)d_in[1];
    const float* inh  = (const float*)d_in[2];
    float* out  = (float*)d_out;

    const int KZ  = 4;
    const int kpg = (N + KZ - 1) / KZ;         // 25
    const int NG  = n / 16;                    // 3000
    const int NG5 = n / 32;                    // 1500
    const size_t needFast = (size_t)B * N * (NG5 + 1) * 4;   // 9.6 MB
    const bool fast = (ws_size >= needFast) && (n % 32 == 0) && (kpg <= 32);

    if (fast) {
        float* scanS = (float*)d_ws;
        k_scan5<<<dim3(N, B), 256, 0, stream>>>(f0, inh, scanS, out, N, n, T, pf);
        const int tiles = (NG * 4 + 255) / 256;            // 47
        k_synth4<<<dim3(tiles, B, KZ), 256, 0, stream>>>(
            harm, f0, inh, scanS, out, B, T, N, n, pf, kpg);
    } else {
        float* f0up = (float*)d_ws;            // B*n floats
        k_f0up<<<dim3((n + 255) / 256, B), 256, 0, stream>>>(f0, f0up, out, T, n, pf);
        const size_t lds_bytes = (size_t)(n / 2) * sizeof(float);  // 96 KB
        k_scan_synth<<<dim3(N, B), 256, lds_bytes, stream>>>(
            harm, f0up, inh, out, B, T, N, n, pf);
    }
}

// Round 9
// 154.072 us; speedup vs baseline: 1.1249x; 1.1249x over previous
//
#include <hip/hip_runtime.h>
#include <cmath>

// ---------------------------------------------------------------------------
// Bit-exact replication of the reference's f32 cumsum TREE (JAX associative
// scan), validated rounds 5-11 (absmax 1.831e-3 — bf16-quantized compare;
// non-chaotic-path deltas <1e-6 are free).
// Round 18 (WIN, 136.7us): S-interface (scan downsweep stops at L5; synth4
//   reconstructs G's in-group, bit-exact). f0up ~8 + scan4 ~35 + synth4
//   49.8 + ~43us dispatch overhead.
// Round 19 (REGRESSED, reverted): fused interp into scan grid = 100x
//   recompute (same class as r16). RULE: nothing sample-indexed computes
//   inside the N-wide grid; f0up stays materialized.
// Round 20: round-18 bodies + ONE change: scan4 never materializes L4.
//   Leaf loop computes two L4 values in registers from f0up float4s (r17-
//   validated bracketing, same loads) and writes L5 directly; LDS 24->12KB
//   (2993 floats) + __launch_bounds__(256,8) -> 8 blk/CU -> 2048 resident
//   >= 1600 launched -> straggler round eliminated.
// ---------------------------------------------------------------------------
#pragma clang fp contract(off)

#define SRF   48000.0f
#define NYQF  21600.0f                    // fp32(48000*0.45), exact
constexpr float  TWO_PI_F  = 6.283185307179586476925286766559f;  // 0x40C90FDB
constexpr double INV_2PI_D = 0.15915494309189533576888376337251;
constexpr float  RC1 = (float)INV_2PI_D;
constexpr float  RC2 = (float)(INV_2PI_D - (double)RC1);
constexpr double INV_SR_D = 1.0 / 48000.0;
constexpr float  DD1 = (float)INV_SR_D;
constexpr float  DD2 = (float)(INV_SR_D - (double)DD1);

__device__ __forceinline__ float hsin_rev(float r) {  // sin(2*pi*r)
#if __has_builtin(__builtin_amdgcn_sinf)
    return __builtin_amdgcn_sinf(r);                  // v_sin_f32: revolutions
#else
    return __sinf(r * TWO_PI_F);
#endif
}

// Correctly-rounded t/48000 via double-float mul (== IEEE f32 divide here;
// proved: no halfway cases, err 2^-47 << 2^-33.5 boundary distance).
__device__ __forceinline__ float div48000(float t) {
    float h = t * DD1;
    float r = __builtin_fmaf(t, DD1, -h);
    float s = __builtin_fmaf(t, DD2, r);
    return h + s;
}

// sin(ph) for f32 ph: double-float reduction to revolutions (|err|<=2^-25 rev)
__device__ __forceinline__ float sin_phase(float ph) {
    float h  = ph * RC1;
    float r  = __builtin_fmaf(ph, RC1, -h);
    float s  = __builtin_fmaf(ph, RC2, r);
    float nn = __builtin_rintf(h);
    float fr = (h - nn) + s;
    return hsin_rev(fr);
}

// group-of-4 broadcast: value of lane (lane&~3)+idx  (idx=0..3 static)
template <int IDX>
__device__ __forceinline__ float grp4_bcast(float v, int lb) {
#if __has_builtin(__builtin_amdgcn_ds_swizzle)
    // BitMode: offset = (xor<<10)|(or<<5)|and ; and=0x1C clears low 2 bits
    constexpr int imm = (IDX << 5) | 0x1C;
    return __int_as_float(__builtin_amdgcn_ds_swizzle(__float_as_int(v), imm));
#else
    return __shfl(v, lb + IDX);
#endif
}

// group-of-8 broadcast: value of lane (lane&~7)
__device__ __forceinline__ float grp8_bcast0(float v, int lane) {
#if __has_builtin(__builtin_amdgcn_ds_swizzle)
    // BitMode: and=0x18 clears low 3 bits, or=0, xor=0
    return __int_as_float(__builtin_amdgcn_ds_swizzle(__float_as_int(v), 0x0018));
#else
    return __shfl(v, lane & ~7);
#endif
}

// kc[b,k] = fp32(k * fp32(sqrt(fp32(1 + fp32(inh*k^2)))))  -- np/jnp-exact
__device__ __forceinline__ float kcval(int k, float ib) {
    float kf = (float)(k + 1);
    float k2 = kf * kf;
    float m  = ib * k2;
    float s1 = 1.0f + m;
    float st = (float)sqrt((double)s1);
    return kf * st;
}

// ---- K1: f0_up[b,j] (np-exact fp32 interp) + zero-init of out --------------
__global__ void __launch_bounds__(256) k_f0up(const float* __restrict__ f0,
        float* __restrict__ f0up, float* __restrict__ out,
        int T, int n, float pf) {
    int j = blockIdx.x * 256 + threadIdx.x;
    int b = blockIdx.y;
    if (j >= n) return;
    float pos = ((float)j + 0.5f);
    pos = pos * pf;
    pos = pos - 0.5f;
    pos = fmaxf(pos, 0.0f);
    pos = fminf(pos, (float)(T - 1));
    int   i0 = (int)pos;
    int   i1 = min(i0 + 1, T - 1);
    float w  = pos - (float)i0;
    float omw = 1.0f - w;
    const float* fb = f0 + b * T;
    f0up[(size_t)b * n + j] = fb[i0] * omw + fb[i1] * w;
    out[(size_t)b * n + j]  = 0.0f;            // harness poisons out; we own it
}

// ---- K2a: per (b,k) L5 scan from f0up; L4 never materialized (12KB LDS) ----
// Emits S rows: sp[0] = 0, sp[1+i] = inclusive-L5-scan[i]  (len5+1 floats).
__global__ void __launch_bounds__(256, 8) k_scan4(const float* __restrict__ f0up,
        const float* __restrict__ inh, float* __restrict__ scanS,
        int N, int n) {
    __shared__ float lv[3008];                 // levels L5..root: 2993 floats
    const int k   = blockIdx.x;
    const int b   = blockIdx.y;
    const int tid = threadIdx.x;
    const float kc = kcval(k, inh[b]);
    const float4* f4 = (const float4*)(f0up + (size_t)b * n);
    const int len5 = n >> 5;

    auto l2of = [&](float4 v) -> float {
        float a0 = div48000(TWO_PI_F * (kc * v.x));
        float a1 = div48000(TWO_PI_F * (kc * v.y));
        float a2 = div48000(TWO_PI_F * (kc * v.z));
        float a3 = div48000(TWO_PI_F * (kc * v.w));
        return (a0 + a1) + (a2 + a3);
    };
    auto l4of = [&](int j) -> float {          // L4 leaf j — r14-validated DAG
        float s01 = l2of(f4[4*j])     + l2of(f4[4*j + 1]);
        float s23 = l2of(f4[4*j + 2]) + l2of(f4[4*j + 3]);
        return s01 + s23;
    };
    for (int i = tid; i < len5; i += 256)
        lv[i] = l4of(2*i) + l4of(2*i + 1);     // L5[i], upsweep bracketing (r17)
    __syncthreads();

    // upsweep L5 -> root (validated pairing/order)
    int offp = 0, lenp = len5, P = 5;
    for (int l = 6; ; ++l) {
        int lenc = lenp >> 1;
        int offc = offp + lenp;
        for (int i = tid; i < lenc; i += 256)
            lv[offc + i] = lv[offp + 2*i] + lv[offp + 2*i + 1];
        __syncthreads();
        P = l;
        if (lenc == 1) break;
        offp = offc; lenp = lenc;
    }
    // downsweep to L5 (round-5-validated formulas, offsets rebased to L5)
    for (int l = P - 1; l >= 5; --l) {
        int lenl = n >> l;
        int offl = 0;
        for (int m = 5; m < l; ++m) offl += (n >> m);
        float*       arr = lv + offl;
        const float* hi  = lv + offl + lenl;
        int lenh = n >> (l + 1);
        for (int i = tid; i < lenh; i += 256) {
            float v = hi[i];
            int e = 2*i + 2;
            if (e < lenl) arr[e] = v + arr[e];
            arr[2*i + 1] = v;
        }
        __syncthreads();
    }
    // lv[0..len5) = inclusive L5 scan; emit padded S row (r18-validated).
    float* sp = scanS + (size_t)(b * N + k) * (len5 + 1);
    if (tid == 0) sp[0] = 0.0f;
    for (int i = tid; i < len5; i += 256) sp[1 + i] = lv[i];
}

// ---- K2b: 4 lanes per 16-j group (byte-exact round-18 body) ----------------
__global__ void __launch_bounds__(256) k_synth4(
        const float* __restrict__ harm, const float* __restrict__ f0up,
        const float* __restrict__ inh,  const float* __restrict__ scanS,
        float* __restrict__ out, int B, int T, int N, int n, float pf, int kpg) {
    const int tid  = threadIdx.x;
    const int b    = blockIdx.y;
    const int k0   = blockIdx.z * kpg;
    const int g    = blockIdx.x * 256 + tid;   // global lane id
    const int q    = g >> 2;                   // 16-sample group
    const int c    = g & 3;                    // quarter within group
    const int NG   = n >> 4;
    const int NG5P = (n >> 5) + 1;             // S-row length
    const int kend = min(k0 + kpg, N);
    const int kact = kend - k0;
    const bool valid = q < NG;
    const bool oddq  = (q & 1) != 0;
    const int  si    = (q >> 1) + (q & 1);     // S index this lane loads

    __shared__ float2 amps[8 * 32];            // (a0, a1-a0) x k (span 1024 j)
    __shared__ float  kcs[32];
    __shared__ float  xp[4][256];              // per-wave transpose for stores

    const float ib    = inh[b];
    const float tmaxf = (float)(T - 1);
    for (int i = tid; i < kact; i += 256) kcs[i] = kcval(k0 + i, ib);

    const int j0blk = blockIdx.x * 1024;
    int i0min;
    {
        float p = ((float)j0blk + 0.5f);
        p = p * pf; p = p - 0.5f;
        p = fmaxf(p, 0.0f); p = fminf(p, tmaxf);
        i0min = (int)p;
    }
    for (int idx = tid; idx < 8 * kact; idx += 256) {
        int r = idx / kact, kk = idx - r * kact;
        int r0 = min(i0min + r, T - 1);
        int r1 = min(i0min + r + 1, T - 1);
        float a0 = harm[((size_t)b * T + r0) * N + (k0 + kk)];
        float a1 = harm[((size_t)b * T + r1) * N + (k0 + kk)];
        amps[idx] = make_float2(a0, a1 - a0);  // blend = fmaf(w, d, a0)
    }
    __syncthreads();                           // last block-wide barrier

    float u0=0.f,u1=0.f,u2=0.f,u3=0.f;
    float w0=0.f,w1=0.f,w2=0.f,w3=0.f;
    int   a0o=0,a1o=0,a2o=0,a3o=0;
    float acc0=0.f, acc1=0.f, acc2=0.f, acc3=0.f;
    float um = __builtin_inff();
    if (valid) {
        const float4 v = *(const float4*)(f0up + (size_t)b * n + (size_t)q * 16 + c * 4);
        u0=v.x; u1=v.y; u2=v.z; u3=v.w;
        um = fminf(fminf(u0,u1), fminf(u2,u3));
        const int jb = q * 16 + c * 4;
        #pragma unroll
        for (int i = 0; i < 4; ++i) {
            float p = ((float)(jb + i) + 0.5f);
            p = p * pf; p = p - 0.5f;
            p = fmaxf(p, 0.0f); p = fminf(p, tmaxf);
            int i0 = (int)p;
            float wv = p - (float)i0;
            int aoo  = (i0 - i0min) * kact;
            if (i==0){w0=wv;a0o=aoo;}
            else if (i==1){w1=wv;a1o=aoo;}
            else if (i==2){w2=wv;a2o=aoo;}
            else {w3=wv;a3o=aoo;}
        }
    }
    // wave-wide min for uniform early break
    #pragma unroll
    for (int off = 32; off > 0; off >>= 1)
        um = fminf(um, __shfl_xor(um, off));
    const float umin = um;
    const int lane = tid & 63;
    const int lb   = lane & ~3;                // group base lane (fallback path)

    if (valid) {
        const float* s4k = scanS + (size_t)(b * N + k0) * NG5P;
        float svc = s4k[si];                   // S[i] (even q) / S[i+1] (odd q)

        for (int k = k0; k < kend; ++k) {
            const int   kk = k - k0;
            const float kc = kcs[kk];
            if (kc * umin >= NYQF) break;      // wave-uniform; kc monotone in k
            const float Sv = svc;
            if (k + 1 < kend) {                // prefetch next k row
                const float* nx = s4k + NG5P;
                svc = nx[si];
                s4k = nx;
            }

            // lane-local increments (bit-exact vs ref elementwise ops)
            float x0 = div48000(TWO_PI_F * (kc * u0));
            float x1 = div48000(TWO_PI_F * (kc * u1));
            float x2 = div48000(TWO_PI_F * (kc * u2));
            float x3 = div48000(TWO_PI_F * (kc * u3));
            float L1p = x0 + x1, L1q = x2 + x3;
            float L2  = L1p + L1q;

            // group L2 partials (FP add commutative bitwise -> exact assoc)
            float s0 = grp4_bcast<0>(L2, lb);
            float s1 = grp4_bcast<1>(L2, lb);
            float s2 = grp4_bcast<2>(L2, lb);
            float s3 = grp4_bcast<3>(L2, lb);
            float t01 = s0 + s1;
            float s23 = s2 + s3;
            float L4v = t01 + s23;             // == l4of bracketing, bit-exact
            // G reconstruction (even lanes compute the deleted downsweep add):
            float G1e = Sv + L4v;              // fl(S[i] + L4[2i]) on even q
            float Gx  = grp8_bcast0(G1e, lane);// supergroup lane0's G1e
            float G0  = oddq ? Gx : Sv;
            float G1  = oddq ? Sv : G1e;

            float b1v = G0 + s0;               // s20
            float b2v = G0 + t01;              // s3v  (g0 + (L2a+L2b))
            float b3v = b2v + s2;              // s22
            float base = (c == 0) ? G0  : (c == 1) ? b1v : (c == 2) ? b2v : b3v;
            float bn   = (c == 0) ? b1v : (c == 1) ? b2v : (c == 2) ? b3v : G1;

            float ph0 = base + x0;
            float ph1 = base + L1p;
            float ph2 = ph1 + x2;
            float ph3 = bn;

            {   float t1 = kc * u0;            // same RN product as ref mask
                if (t1 < NYQF) { float sv = sin_phase(ph0);
                    float2 a = amps[a0o + kk];
                    acc0 = __builtin_fmaf(__builtin_fmaf(w0, a.y, a.x), sv, acc0); } }
            {   float t1 = kc * u1;
                if (t1 < NYQF) { float sv = sin_phase(ph1);
                    float2 a = amps[a1o + kk];
                    acc1 = __builtin_fmaf(__builtin_fmaf(w1, a.y, a.x), sv, acc1); } }
            {   float t1 = kc * u2;
                if (t1 < NYQF) { float sv = sin_phase(ph2);
                    float2 a = amps[a2o + kk];
                    acc2 = __builtin_fmaf(__builtin_fmaf(w2, a.y, a.x), sv, acc2); } }
            {   float t1 = kc * u3;
                if (t1 < NYQF) { float sv = sin_phase(ph3);
                    float2 a = amps[a3o + kk];
                    acc3 = __builtin_fmaf(__builtin_fmaf(w3, a.y, a.x), sv, acc3); } }
        }
    }

    // ---- wave-local transpose epilogue: coalesce atomics to full 64B lines.
    // Lane l owns floats 4l..4l+3 of its wave's contiguous 1KB out span; the
    // LDS bounce makes each atomic instruction cover 64 consecutive words.
    // Per-wave LDS region -> no barrier needed (lgkmcnt orders write->read).
    {
        const int wid  = tid >> 6;
        *(float4*)&xp[wid][4 * lane] = make_float4(acc0, acc1, acc2, acc3);
        const float Nf = (float)N;
        const int jb = blockIdx.x * 1024 + wid * 256;   // wave span [jb, jb+256)
        float* ob = out + (size_t)b * n + jb;
        #pragma unroll
        for (int i = 0; i < 4; ++i) {
            float v  = xp[wid][i * 64 + lane];
            int   jj = jb + i * 64 + lane;
            if (jj < n) atomicAdd(&ob[i * 64 + lane], v / Nf);
        }
    }
}

// ---- Fallback: round-5 proven kernel (atomics, 96 KB LDS) ------------------
__global__ void __launch_bounds__(256) k_scan_synth(
        const float* __restrict__ harm, const float* __restrict__ f0up,
        const float* __restrict__ inh,  float* __restrict__ out,
        int B, int T, int N, int n, float pf) {
    extern __shared__ float lv[];
    const int k   = blockIdx.x;
    const int b   = blockIdx.y;
    const int tid = threadIdx.x;
    const float kc = kcval(k, inh[b]);
    const float* fb = f0up + (size_t)b * n;

    auto inc = [&](int j) -> float {
        float u    = fb[j];
        float inst = kc * u;
        float tt   = TWO_PI_F * inst;
        return tt / SRF;
    };

    const int len1 = n >> 1;
    {
        const float4* f4 = (const float4*)fb;
        for (int i = tid; i < (n >> 2); i += 256) {
            float4 u = f4[i];
            float a0 = (TWO_PI_F * (kc * u.x)) / SRF;
            float a1 = (TWO_PI_F * (kc * u.y)) / SRF;
            float a2 = (TWO_PI_F * (kc * u.z)) / SRF;
            float a3 = (TWO_PI_F * (kc * u.w)) / SRF;
            lv[i] = (a0 + a1) + (a2 + a3);
        }
    }
    __syncthreads();
    int offp = 0, lenp = n >> 2, P = 2;
    for (int l = 3; ; ++l) {
        int lenc = lenp >> 1;
        int offc = offp + lenp;
        for (int i = tid; i < lenc; i += 256)
            lv[offc + i] = lv[offp + 2*i] + lv[offp + 2*i + 1];
        __syncthreads();
        P = l;
        if (lenc == 1) break;
        offp = offc; lenp = lenc;
    }
    for (int l = P - 1; l >= 2; --l) {
        int lenl = n >> l;
        int offl = 0;
        for (int m = 2; m < l; ++m) offl += (n >> m);
        float*       arr = lv + offl;
        const float* hi  = lv + offl + lenl;
        int lenh = n >> (l + 1);
        for (int i = tid; i < lenh; i += 256) {
            float v = hi[i];
            int e = 2*i + 2;
            if (e < lenl) arr[e] = v + arr[e];
            arr[2*i + 1] = v;
        }
        __syncthreads();
    }
    const float* scan2 = lv;

    const float  tmaxf = (float)(T - 1);
    const float  invN  = 1.0f / (float)N;
    const float* hb    = harm + (size_t)b * T * N + k;
    float*       ob    = out + (size_t)b * n;

    auto emit = [&](int j, float ph) {
        float u    = fb[j];
        float inst = kc * u;
        if (!(inst < NYQF)) return;
        double pr = (double)ph * INV_2PI_D;
        double fr = pr - rint(pr);
        float  sv = hsin_rev((float)fr);
        float pos = ((float)j + 0.5f);
        pos = pos * pf; pos = pos - 0.5f;
        pos = fmaxf(pos, 0.0f); pos = fminf(pos, tmaxf);
        int   i0 = (int)pos;
        int   i1 = min(i0 + 1, T - 1);
        float w  = pos - (float)i0;
        float a  = hb[(size_t)i0 * N] * (1.0f - w) + hb[(size_t)i1 * N] * w;
        atomicAdd(&ob[j], (a * sv) * invN);
    };

    if (tid == 0) emit(0, inc(0));
    for (int tt = tid; tt < len1; tt += 256) {
        float s1;
        if (tt == 0)      s1 = inc(0) + inc(1);
        else if (tt & 1)  s1 = scan2[(tt - 1) >> 1];
        else              s1 = scan2[(tt >> 1) - 1] + (inc(2*tt) + inc(2*tt + 1));
        emit(2*tt + 1, s1);
        int je = 2*tt + 2;
        if (je < n) emit(je, s1 + inc(je));
    }
}

extern "C" void kernel_launch(void* const* d_in, const int* in_sizes, int n_in,
                              void* d_out, int out_size, void* d_ws, size_t ws_size,
                              hipStream_t stream) {
    const int B = in_sizes[2];                 // 16
    const int T = in_sizes[1] / B;             // 250
    const int N = in_sizes[0] / (B * T);       // 100
    const int n = out_size / B;                // 48000
    const float pf = (float)((double)T / (double)n);

    const float* harm = (const float*)d_in[0];
    const float* f0   = (const float*)d_in[1];
    const float* inh  = (const float*)d_in[2];
    float* out  = (float*)d_out;
    float* f0up = (float*)d_ws;                // B*n floats = 3.07 MB

    const int KZ  = 4;
    const int kpg = (N + KZ - 1) / KZ;         // 25
    const int NG  = n / 16;                    // 3000
    const int NG5 = n / 32;                    // 1500
    const size_t needFast = (size_t)B * n * 4 + (size_t)B * N * (NG5 + 1) * 4;
    const bool fast = (ws_size >= needFast) && (n % 32 == 0) && (kpg <= 32);

    k_f0up<<<dim3((n + 255) / 256, B), 256, 0, stream>>>(f0, f0up, out, T, n, pf);

    if (fast) {
        float* scanS = (float*)((char*)d_ws + (size_t)B * n * 4);
        k_scan4<<<dim3(N, B), 256, 0, stream>>>(f0up, inh, scanS, N, n);
        const int tiles = (NG * 4 + 255) / 256;            // 47
        k_synth4<<<dim3(tiles, B, KZ), 256, 0, stream>>>(
            harm, f0up, inh, scanS, out, B, T, N, n, pf, kpg);
    } else {
        const size_t lds_bytes = (size_t)(n / 2) * sizeof(float);  // 96 KB
        k_scan_synth<<<dim3(N, B), 256, lds_bytes, stream>>>(
            harm, f0up, inh, out, B, T, N, n, pf);
    }
}

// Round 11
// 135.896 us; speedup vs baseline: 1.2753x; 1.1337x over previous
//
#include <hip/hip_runtime.h>
#include <cmath>

// ---------------------------------------------------------------------------
// Bit-exact replication of the reference's f32 cumsum TREE (JAX associative
// scan), validated rounds 5-11 (absmax 1.831e-3 — bf16-quantized compare;
// non-chaotic-path deltas <1e-6 are free).
// Round 18 (WIN, 136.7us): S-interface. f0up ~8 + scan4 ~35 + synth4 ~50
//   + ~44us dispatch overhead.
// Round 20 (REGRESSED): 12KB scan4 + __launch_bounds__(256,8): straggler
//   removed but scan4 ~50us (inferred) — the forced <=64-VGPR cap serializes
//   the 8-float4 leaf (r17 precedent: same bound -> VGPR 32, VALUBusy 22%).
// Round 21: keep 12KB LDS (straggler fix) but restore r18's leaf codegen
//   shape: ONE l4of per thread per iter (4 loads in flight, natural ~44
//   VGPR) + lane-pair ds_swizzle to form L5[i] = fl(L4[2i]+L4[2i+1]) —
//   identical bracketing as r17/r20-validated L5 (bit-exact). Plain
//   __launch_bounds__(256): at <=64 VGPR HW grants 8 blk/CU anyway ->
//   2048 resident >= 1600 -> single round, allocator unstrangled.
//   Tree/emit/synth4 byte-identical to r20 (bit-correct, absmax exact).
// Round 22: resubmit unchanged — round-21 bench was an infra failure
//   (container died twice; no compile/correctness signal). Leaf pair-swizzle
//   re-audited: final-iteration active prefix = 184 lanes (even), pairs
//   never straddle the active edge or a wave boundary.
// ---------------------------------------------------------------------------
#pragma clang fp contract(off)

#define SRF   48000.0f
#define NYQF  21600.0f                    // fp32(48000*0.45), exact
constexpr float  TWO_PI_F  = 6.283185307179586476925286766559f;  // 0x40C90FDB
constexpr double INV_2PI_D = 0.15915494309189533576888376337251;
constexpr float  RC1 = (float)INV_2PI_D;
constexpr float  RC2 = (float)(INV_2PI_D - (double)RC1);
constexpr double INV_SR_D = 1.0 / 48000.0;
constexpr float  DD1 = (float)INV_SR_D;
constexpr float  DD2 = (float)(INV_SR_D - (double)DD1);

__device__ __forceinline__ float hsin_rev(float r) {  // sin(2*pi*r)
#if __has_builtin(__builtin_amdgcn_sinf)
    return __builtin_amdgcn_sinf(r);                  // v_sin_f32: revolutions
#else
    return __sinf(r * TWO_PI_F);
#endif
}

// Correctly-rounded t/48000 via double-float mul (== IEEE f32 divide here;
// proved: no halfway cases, err 2^-47 << 2^-33.5 boundary distance).
__device__ __forceinline__ float div48000(float t) {
    float h = t * DD1;
    float r = __builtin_fmaf(t, DD1, -h);
    float s = __builtin_fmaf(t, DD2, r);
    return h + s;
}

// sin(ph) for f32 ph: double-float reduction to revolutions (|err|<=2^-25 rev)
__device__ __forceinline__ float sin_phase(float ph) {
    float h  = ph * RC1;
    float r  = __builtin_fmaf(ph, RC1, -h);
    float s  = __builtin_fmaf(ph, RC2, r);
    float nn = __builtin_rintf(h);
    float fr = (h - nn) + s;
    return hsin_rev(fr);
}

// group-of-4 broadcast: value of lane (lane&~3)+idx  (idx=0..3 static)
template <int IDX>
__device__ __forceinline__ float grp4_bcast(float v, int lb) {
#if __has_builtin(__builtin_amdgcn_ds_swizzle)
    // BitMode: offset = (xor<<10)|(or<<5)|and ; and=0x1C clears low 2 bits
    constexpr int imm = (IDX << 5) | 0x1C;
    return __int_as_float(__builtin_amdgcn_ds_swizzle(__float_as_int(v), imm));
#else
    return __shfl(v, lb + IDX);
#endif
}

// group-of-8 broadcast: value of lane (lane&~7)
__device__ __forceinline__ float grp8_bcast0(float v, int lane) {
#if __has_builtin(__builtin_amdgcn_ds_swizzle)
    // BitMode: and=0x18 clears low 3 bits, or=0, xor=0
    return __int_as_float(__builtin_amdgcn_ds_swizzle(__float_as_int(v), 0x0018));
#else
    return __shfl(v, lane & ~7);
#endif
}

// lane-pair swap: exchange values of lanes 2m <-> 2m+1 (xor 1)
__device__ __forceinline__ float pair_swap(float v) {
#if __has_builtin(__builtin_amdgcn_ds_swizzle)
    // BitMode: xor=1, and=0x1F
    return __int_as_float(__builtin_amdgcn_ds_swizzle(__float_as_int(v), 0x041F));
#else
    return __shfl_xor(v, 1);
#endif
}

// kc[b,k] = fp32(k * fp32(sqrt(fp32(1 + fp32(inh*k^2)))))  -- np/jnp-exact
__device__ __forceinline__ float kcval(int k, float ib) {
    float kf = (float)(k + 1);
    float k2 = kf * kf;
    float m  = ib * k2;
    float s1 = 1.0f + m;
    float st = (float)sqrt((double)s1);
    return kf * st;
}

// ---- K1: f0_up[b,j] (np-exact fp32 interp) + zero-init of out --------------
__global__ void __launch_bounds__(256) k_f0up(const float* __restrict__ f0,
        float* __restrict__ f0up, float* __restrict__ out,
        int T, int n, float pf) {
    int j = blockIdx.x * 256 + threadIdx.x;
    int b = blockIdx.y;
    if (j >= n) return;
    float pos = ((float)j + 0.5f);
    pos = pos * pf;
    pos = pos - 0.5f;
    pos = fmaxf(pos, 0.0f);
    pos = fminf(pos, (float)(T - 1));
    int   i0 = (int)pos;
    int   i1 = min(i0 + 1, T - 1);
    float w  = pos - (float)i0;
    float omw = 1.0f - w;
    const float* fb = f0 + b * T;
    f0up[(size_t)b * n + j] = fb[i0] * omw + fb[i1] * w;
    out[(size_t)b * n + j]  = 0.0f;            // harness poisons out; we own it
}

// ---- K2a: per (b,k) L5 scan from f0up; L4 via lane-pair swizzle (12KB) -----
// Emits S rows: sp[0] = 0, sp[1+i] = inclusive-L5-scan[i]  (len5+1 floats).
__global__ void __launch_bounds__(256) k_scan4(const float* __restrict__ f0up,
        const float* __restrict__ inh, float* __restrict__ scanS,
        int N, int n) {
    __shared__ float lv[3008];                 // levels L5..root: 2993 floats
    const int k   = blockIdx.x;
    const int b   = blockIdx.y;
    const int tid = threadIdx.x;
    const float kc = kcval(k, inh[b]);
    const float4* f4 = (const float4*)(f0up + (size_t)b * n);
    const int len4 = n >> 4;
    const int len5 = n >> 5;

    auto l2of = [&](float4 v) -> float {
        float a0 = div48000(TWO_PI_F * (kc * v.x));
        float a1 = div48000(TWO_PI_F * (kc * v.y));
        float a2 = div48000(TWO_PI_F * (kc * v.z));
        float a3 = div48000(TWO_PI_F * (kc * v.w));
        return (a0 + a1) + (a2 + a3);
    };
    auto l4of = [&](int j) -> float {          // L4 leaf j — r14-validated DAG
        float s01 = l2of(f4[4*j])     + l2of(f4[4*j + 1]);
        float s23 = l2of(f4[4*j + 2]) + l2of(f4[4*j + 3]);
        return s01 + s23;
    };
    // Leaf: one l4of per thread per iter (r18 codegen shape, 4 loads in
    // flight); L5 formed by lane-pair swizzle. Even leaf index writes
    // lv[i>>1] = fl(L4[2i] + L4[2i+1]) — r17/r20-validated bracketing.
    // len4 even and stride 256 even => pairs never straddle the active edge.
    for (int i = tid; i < len4; i += 256) {
        float v  = l4of(i);
        float vp = pair_swap(v);
        if ((i & 1) == 0) lv[i >> 1] = v + vp;
    }
    __syncthreads();

    // upsweep L5 -> root (validated pairing/order)
    int offp = 0, lenp = len5, P = 5;
    for (int l = 6; ; ++l) {
        int lenc = lenp >> 1;
        int offc = offp + lenp;
        for (int i = tid; i < lenc; i += 256)
            lv[offc + i] = lv[offp + 2*i] + lv[offp + 2*i + 1];
        __syncthreads();
        P = l;
        if (lenc == 1) break;
        offp = offc; lenp = lenc;
    }
    // downsweep to L5 (round-5-validated formulas, offsets rebased to L5)
    for (int l = P - 1; l >= 5; --l) {
        int lenl = n >> l;
        int offl = 0;
        for (int m = 5; m < l; ++m) offl += (n >> m);
        float*       arr = lv + offl;
        const float* hi  = lv + offl + lenl;
        int lenh = n >> (l + 1);
        for (int i = tid; i < lenh; i += 256) {
            float v = hi[i];
            int e = 2*i + 2;
            if (e < lenl) arr[e] = v + arr[e];
            arr[2*i + 1] = v;
        }
        __syncthreads();
    }
    // lv[0..len5) = inclusive L5 scan; emit padded S row (r18-validated).
    float* sp = scanS + (size_t)(b * N + k) * (len5 + 1);
    if (tid == 0) sp[0] = 0.0f;
    for (int i = tid; i < len5; i += 256) sp[1 + i] = lv[i];
}

// ---- K2b: 4 lanes per 16-j group (byte-exact round-18 body) ----------------
__global__ void __launch_bounds__(256) k_synth4(
        const float* __restrict__ harm, const float* __restrict__ f0up,
        const float* __restrict__ inh,  const float* __restrict__ scanS,
        float* __restrict__ out, int B, int T, int N, int n, float pf, int kpg) {
    const int tid  = threadIdx.x;
    const int b    = blockIdx.y;
    const int k0   = blockIdx.z * kpg;
    const int g    = blockIdx.x * 256 + tid;   // global lane id
    const int q    = g >> 2;                   // 16-sample group
    const int c    = g & 3;                    // quarter within group
    const int NG   = n >> 4;
    const int NG5P = (n >> 5) + 1;             // S-row length
    const int kend = min(k0 + kpg, N);
    const int kact = kend - k0;
    const bool valid = q < NG;
    const bool oddq  = (q & 1) != 0;
    const int  si    = (q >> 1) + (q & 1);     // S index this lane loads

    __shared__ float2 amps[8 * 32];            // (a0, a1-a0) x k (span 1024 j)
    __shared__ float  kcs[32];
    __shared__ float  xp[4][256];              // per-wave transpose for stores

    const float ib    = inh[b];
    const float tmaxf = (float)(T - 1);
    for (int i = tid; i < kact; i += 256) kcs[i] = kcval(k0 + i, ib);

    const int j0blk = blockIdx.x * 1024;
    int i0min;
    {
        float p = ((float)j0blk + 0.5f);
        p = p * pf; p = p - 0.5f;
        p = fmaxf(p, 0.0f); p = fminf(p, tmaxf);
        i0min = (int)p;
    }
    for (int idx = tid; idx < 8 * kact; idx += 256) {
        int r = idx / kact, kk = idx - r * kact;
        int r0 = min(i0min + r, T - 1);
        int r1 = min(i0min + r + 1, T - 1);
        float a0 = harm[((size_t)b * T + r0) * N + (k0 + kk)];
        float a1 = harm[((size_t)b * T + r1) * N + (k0 + kk)];
        amps[idx] = make_float2(a0, a1 - a0);  // blend = fmaf(w, d, a0)
    }
    __syncthreads();                           // last block-wide barrier

    float u0=0.f,u1=0.f,u2=0.f,u3=0.f;
    float w0=0.f,w1=0.f,w2=0.f,w3=0.f;
    int   a0o=0,a1o=0,a2o=0,a3o=0;
    float acc0=0.f, acc1=0.f, acc2=0.f, acc3=0.f;
    float um = __builtin_inff();
    if (valid) {
        const float4 v = *(const float4*)(f0up + (size_t)b * n + (size_t)q * 16 + c * 4);
        u0=v.x; u1=v.y; u2=v.z; u3=v.w;
        um = fminf(fminf(u0,u1), fminf(u2,u3));
        const int jb = q * 16 + c * 4;
        #pragma unroll
        for (int i = 0; i < 4; ++i) {
            float p = ((float)(jb + i) + 0.5f);
            p = p * pf; p = p - 0.5f;
            p = fmaxf(p, 0.0f); p = fminf(p, tmaxf);
            int i0 = (int)p;
            float wv = p - (float)i0;
            int aoo  = (i0 - i0min) * kact;
            if (i==0){w0=wv;a0o=aoo;}
            else if (i==1){w1=wv;a1o=aoo;}
            else if (i==2){w2=wv;a2o=aoo;}
            else {w3=wv;a3o=aoo;}
        }
    }
    // wave-wide min for uniform early break
    #pragma unroll
    for (int off = 32; off > 0; off >>= 1)
        um = fminf(um, __shfl_xor(um, off));
    const float umin = um;
    const int lane = tid & 63;
    const int lb   = lane & ~3;                // group base lane (fallback path)

    if (valid) {
        const float* s4k = scanS + (size_t)(b * N + k0) * NG5P;
        float svc = s4k[si];                   // S[i] (even q) / S[i+1] (odd q)

        for (int k = k0; k < kend; ++k) {
            const int   kk = k - k0;
            const float kc = kcs[kk];
            if (kc * umin >= NYQF) break;      // wave-uniform; kc monotone in k
            const float Sv = svc;
            if (k + 1 < kend) {                // prefetch next k row
                const float* nx = s4k + NG5P;
                svc = nx[si];
                s4k = nx;
            }

            // lane-local increments (bit-exact vs ref elementwise ops)
            float x0 = div48000(TWO_PI_F * (kc * u0));
            float x1 = div48000(TWO_PI_F * (kc * u1));
            float x2 = div48000(TWO_PI_F * (kc * u2));
            float x3 = div48000(TWO_PI_F * (kc * u3));
            float L1p = x0 + x1, L1q = x2 + x3;
            float L2  = L1p + L1q;

            // group L2 partials (FP add commutative bitwise -> exact assoc)
            float s0 = grp4_bcast<0>(L2, lb);
            float s1 = grp4_bcast<1>(L2, lb);
            float s2 = grp4_bcast<2>(L2, lb);
            float s3 = grp4_bcast<3>(L2, lb);
            float t01 = s0 + s1;
            float s23 = s2 + s3;
            float L4v = t01 + s23;             // == l4of bracketing, bit-exact
            // G reconstruction (even lanes compute the deleted downsweep add):
            float G1e = Sv + L4v;              // fl(S[i] + L4[2i]) on even q
            float Gx  = grp8_bcast0(G1e, lane);// supergroup lane0's G1e
            float G0  = oddq ? Gx : Sv;
            float G1  = oddq ? Sv : G1e;

            float b1v = G0 + s0;               // s20
            float b2v = G0 + t01;              // s3v  (g0 + (L2a+L2b))
            float b3v = b2v + s2;              // s22
            float base = (c == 0) ? G0  : (c == 1) ? b1v : (c == 2) ? b2v : b3v;
            float bn   = (c == 0) ? b1v : (c == 1) ? b2v : (c == 2) ? b3v : G1;

            float ph0 = base + x0;
            float ph1 = base + L1p;
            float ph2 = ph1 + x2;
            float ph3 = bn;

            {   float t1 = kc * u0;            // same RN product as ref mask
                if (t1 < NYQF) { float sv = sin_phase(ph0);
                    float2 a = amps[a0o + kk];
                    acc0 = __builtin_fmaf(__builtin_fmaf(w0, a.y, a.x), sv, acc0); } }
            {   float t1 = kc * u1;
                if (t1 < NYQF) { float sv = sin_phase(ph1);
                    float2 a = amps[a1o + kk];
                    acc1 = __builtin_fmaf(__builtin_fmaf(w1, a.y, a.x), sv, acc1); } }
            {   float t1 = kc * u2;
                if (t1 < NYQF) { float sv = sin_phase(ph2);
                    float2 a = amps[a2o + kk];
                    acc2 = __builtin_fmaf(__builtin_fmaf(w2, a.y, a.x), sv, acc2); } }
            {   float t1 = kc * u3;
                if (t1 < NYQF) { float sv = sin_phase(ph3);
                    float2 a = amps[a3o + kk];
                    acc3 = __builtin_fmaf(__builtin_fmaf(w3, a.y, a.x), sv, acc3); } }
        }
    }

    // ---- wave-local transpose epilogue: coalesce atomics to full 64B lines.
    // Lane l owns floats 4l..4l+3 of its wave's contiguous 1KB out span; the
    // LDS bounce makes each atomic instruction cover 64 consecutive words.
    // Per-wave LDS region -> no barrier needed (lgkmcnt orders write->read).
    {
        const int wid  = tid >> 6;
        *(float4*)&xp[wid][4 * lane] = make_float4(acc0, acc1, acc2, acc3);
        const float Nf = (float)N;
        const int jb = blockIdx.x * 1024 + wid * 256;   // wave span [jb, jb+256)
        float* ob = out + (size_t)b * n + jb;
        #pragma unroll
        for (int i = 0; i < 4; ++i) {
            float v  = xp[wid][i * 64 + lane];
            int   jj = jb + i * 64 + lane;
            if (jj < n) atomicAdd(&ob[i * 64 + lane], v / Nf);
        }
    }
}

// ---- Fallback: round-5 proven kernel (atomics, 96 KB LDS) ------------------
__global__ void __launch_bounds__(256) k_scan_synth(
        const float* __restrict__ harm, const float* __restrict__ f0up,
        const float* __restrict__ inh,  float* __restrict__ out,
        int B, int T, int N, int n, float pf) {
    extern __shared__ float lv[];
    const int k   = blockIdx.x;
    const int b   = blockIdx.y;
    const int tid = threadIdx.x;
    const float kc = kcval(k, inh[b]);
    const float* fb = f0up + (size_t)b * n;

    auto inc = [&](int j) -> float {
        float u    = fb[j];
        float inst = kc * u;
        float tt   = TWO_PI_F * inst;
        return tt / SRF;
    };

    const int len1 = n >> 1;
    {
        const float4* f4 = (const float4*)fb;
        for (int i = tid; i < (n >> 2); i += 256) {
            float4 u = f4[i];
            float a0 = (TWO_PI_F * (kc * u.x)) / SRF;
            float a1 = (TWO_PI_F * (kc * u.y)) / SRF;
            float a2 = (TWO_PI_F * (kc * u.z)) / SRF;
            float a3 = (TWO_PI_F * (kc * u.w)) / SRF;
            lv[i] = (a0 + a1) + (a2 + a3);
        }
    }
    __syncthreads();
    int offp = 0, lenp = n >> 2, P = 2;
    for (int l = 3; ; ++l) {
        int lenc = lenp >> 1;
        int offc = offp + lenp;
        for (int i = tid; i < lenc; i += 256)
            lv[offc + i] = lv[offp + 2*i] + lv[offp + 2*i + 1];
        __syncthreads();
        P = l;
        if (lenc == 1) break;
        offp = offc; lenp = lenc;
    }
    for (int l = P - 1; l >= 2; --l) {
        int lenl = n >> l;
        int offl = 0;
        for (int m = 2; m < l; ++m) offl += (n >> m);
        float*       arr = lv + offl;
        const float* hi  = lv + offl + lenl;
        int lenh = n >> (l + 1);
        for (int i = tid; i < lenh; i += 256) {
            float v = hi[i];
            int e = 2*i + 2;
            if (e < lenl) arr[e] = v + arr[e];
            arr[2*i + 1] = v;
        }
        __syncthreads();
    }
    const float* scan2 = lv;

    const float  tmaxf = (float)(T - 1);
    const float  invN  = 1.0f / (float)N;
    const float* hb    = harm + (size_t)b * T * N + k;
    float*       ob    = out + (size_t)b * n;

    auto emit = [&](int j, float ph) {
        float u    = fb[j];
        float inst = kc * u;
        if (!(inst < NYQF)) return;
        double pr = (double)ph * INV_2PI_D;
        double fr = pr - rint(pr);
        float  sv = hsin_rev((float)fr);
        float pos = ((float)j + 0.5f);
        pos = pos * pf; pos = pos - 0.5f;
        pos = fmaxf(pos, 0.0f); pos = fminf(pos, tmaxf);
        int   i0 = (int)pos;
        int   i1 = min(i0 + 1, T - 1);
        float w  = pos - (float)i0;
        float a  = hb[(size_t)i0 * N] * (1.0f - w) + hb[(size_t)i1 * N] * w;
        atomicAdd(&ob[j], (a * sv) * invN);
    };

    if (tid == 0) emit(0, inc(0));
    for (int tt = tid; tt < len1; tt += 256) {
        float s1;
        if (tt == 0)      s1 = inc(0) + inc(1);
        else if (tt & 1)  s1 = scan2[(tt - 1) >> 1];
        else              s1 = scan2[(tt >> 1) - 1] + (inc(2*tt) + inc(2*tt + 1));
        emit(2*tt + 1, s1);
        int je = 2*tt + 2;
        if (je < n) emit(je, s1 + inc(je));
    }
}

extern "C" void kernel_launch(void* const* d_in, const int* in_sizes, int n_in,
                              void* d_out, int out_size, void* d_ws, size_t ws_size,
                              hipStream_t stream) {
    const int B = in_sizes[2];                 // 16
    const int T = in_sizes[1] / B;             // 250
    const int N = in_sizes[0] / (B * T);       // 100
    const int n = out_size / B;                // 48000
    const float pf = (float)((double)T / (double)n);

    const float* harm = (const float*)d_in[0];
    const float* f0   = (const float*)d_in[1];
    const float* inh  = (const float*)d_in[2];
    float* out  = (float*)d_out;
    float* f0up = (float*)d_ws;                // B*n floats = 3.07 MB

    const int KZ  = 4;
    const int kpg = (N + KZ - 1) / KZ;         // 25
    const int NG  = n / 16;                    // 3000
    const int NG5 = n / 32;                    // 1500
    const size_t needFast = (size_t)B * n * 4 + (size_t)B * N * (NG5 + 1) * 4;
    const bool fast = (ws_size >= needFast) && (n % 32 == 0) && (kpg <= 32);

    k_f0up<<<dim3((n + 255) / 256, B), 256, 0, stream>>>(f0, f0up, out, T, n, pf);

    if (fast) {
        float* scanS = (float*)((char*)d_ws + (size_t)B * n * 4);
        k_scan4<<<dim3(N, B), 256, 0, stream>>>(f0up, inh, scanS, N, n);
        const int tiles = (NG * 4 + 255) / 256;            // 47
        k_synth4<<<dim3(tiles, B, KZ), 256, 0, stream>>>(
            harm, f0up, inh, scanS, out, B, T, N, n, pf, kpg);
    } else {
        const size_t lds_bytes = (size_t)(n / 2) * sizeof(float);  // 96 KB
        k_scan_synth<<<dim3(N, B), 256, lds_bytes, stream>>>(
            harm, f0up, inh, out, B, T, N, n, pf);
    }
}